// Round 6
// baseline (160.974 us; speedup 1.0000x reference)
//
#include <hip/hip_runtime.h>

// SSIM, N=32 images 512x512 fp32, 11x11 Gaussian (separable via rank-1
// window), zero pad, scalar mean output.
//
// R6: barrier-free wave-private rework. R5 post-mortem: halving LDS traffic
// left dur unchanged (61us) while VALUBusy rose to 54% -> limiter is the
// per-row __syncthreads (couples waves to slowest load + full waitcnt
// drain), not any pipe's bandwidth.
//  - Each WAVE owns a 64-col band and stages its own (s,d)=(x+y,x-y) row
//    (plus its own 10 halo cols, threads 0..9, redundant across waves)
//    into a wave-private LDS region. Within a wave, ds_write->ds_read is
//    ordered by the DS pipe + compiler lgkmcnt: NO barrier, NO dbuf.
//  - 4 independent waves per 256-thread block; 8 bands x 16 chunks x
//    32 imgs = 4096 free-running waves = 16/CU.
//  - Per-tap s^2,d^2 recover all moments (R5 math, verified absmax 0).
//  - Prefetch 1 row ahead; 44-reg vertical ring, mod-11 static via 11x
//    unroll; per-wave shuffle reduce + 1 atomicAdd per wave.
// No min-waves launch_bounds (R3's 64-VGPR cap caused 244MB scratch spill).

#define IMG_H 512
#define IMG_W 512
#define NIMG  32
#define WC    64               // columns per wave
#define RROWS 32               // output rows per wave
#define ITERS (RROWS + 10)     // 42 input rows streamed
#define LDSW  80               // 74 used (5 halo + 64 + 5 halo), padded

#define C1F  1.0e-4f
#define C2F  9.0e-4f
#define EPSF 1.0e-8f

__global__ __launch_bounds__(256) void ssim_kernel(
    const float* __restrict__ xg, const float* __restrict__ yg,
    const float* __restrict__ wg, float* __restrict__ out)
{
    const int t    = threadIdx.x;       // 0..255
    const int w    = t >> 6;            // wave in block, 0..3
    const int lane = t & 63;
    const int band = blockIdx.x * 4 + w;   // 0..7
    const int chnk = blockIdx.y;           // 0..15
    const int img  = blockIdx.z;           // 0..31
    const int c0   = band * WC;
    const int r0   = chnk * RROWS;

    const float* xb = xg + (size_t)img * (IMG_H * IMG_W);
    const float* yb = yg + (size_t)img * (IMG_H * IMG_W);

    __shared__ float2 ssd[4][LDSW];     // wave-private regions

    // 1D taps = row sums of normalized 2D window -> SGPRs via readfirstlane.
    // Per-wave computation: no cross-wave interaction, no barrier.
    float rs = 0.f;
    if (lane < 11) {
        #pragma unroll
        for (int j = 0; j < 11; ++j) rs += wg[lane * 11 + j];
    }
    float g[11];
    #pragma unroll
    for (int k = 0; k < 11; ++k) {
        int gi = __shfl(__float_as_int(rs), k, 64);
        g[k] = __int_as_float(__builtin_amdgcn_readfirstlane(gi));
    }

    const int colA = c0 + lane;                   // own column, in [0,512)
    const int  b2     = (lane < 5) ? lane : (WC + lane); // halo slot (lane<10)
    const int  colB   = c0 - 5 + b2;
    const bool hasB   = (lane < 10);
    const bool colBok = hasB && ((unsigned)colB < IMG_W);

    // vertical register rings: 4 planes x 11 rows = 44 VGPRs
    float rS[11], rD[11], rS2[11], rD2[11];

    // preload first input row (r0 - 5)
    float lxA, lyA, lxB, lyB;
    {
        const int r = r0 - 5;
        const bool rv = ((unsigned)r < IMG_H);
        const float* xr = xb + (size_t)r * IMG_W;
        const float* yr = yb + (size_t)r * IMG_W;
        lxA = rv ? xr[colA] : 0.f;
        lyA = rv ? yr[colA] : 0.f;
        lxB = (rv && colBok) ? xr[colB] : 0.f;
        lyB = (rv && colBok) ? yr[colB] : 0.f;
    }

    float acc = 0.f;

    for (int ii = 0; ii < 44; ii += 11) {
        #pragma unroll
        for (int s = 0; s < 11; ++s) {
            const int i = ii + s;
            if (i < ITERS) {
                // stage own column (+ halo col for lane<10) in (s,d) basis
                ssd[w][5 + lane] = make_float2(lxA + lyA, lxA - lyA);
                if (hasB)
                    ssd[w][b2] = make_float2(lxB + lyB, lxB - lyB);
                // NO barrier: wave-private region, DS pipe is in-order per
                // wave and compiler inserts lgkmcnt for the RAW below.

                // prefetch next input row (consumed next iteration)
                {
                    const int r = r0 - 4 + i;
                    const bool rv = ((unsigned)r < IMG_H);
                    const float* xr = xb + (size_t)r * IMG_W;
                    const float* yr = yb + (size_t)r * IMG_W;
                    lxA = rv ? xr[colA] : 0.f;
                    lyA = rv ? yr[colA] : 0.f;
                    lxB = (rv && colBok) ? xr[colB] : 0.f;
                    lyB = (rv && colBok) ? yr[colB] : 0.f;
                }

                // horizontal 11-tap conv: per tap load (s,d), square, 4 FMA
                float hS = 0.f, hD = 0.f, hS2 = 0.f, hD2 = 0.f;
                #pragma unroll
                for (int k = 0; k < 11; ++k) {
                    const float2 v = ssd[w][lane + k];
                    hS  = fmaf(g[k], v.x, hS);
                    hD  = fmaf(g[k], v.y, hD);
                    hS2 = fmaf(g[k], v.x * v.x, hS2);
                    hD2 = fmaf(g[k], v.y * v.y, hD2);
                }
                rS[s] = hS; rD[s] = hD; rS2[s] = hS2; rD2[s] = hD2;

                if (i >= 10) {                  // output row r0 + i - 10
                    float mS = 0.f, mD = 0.f, mS2 = 0.f, mD2 = 0.f;
                    #pragma unroll
                    for (int j = 0; j < 11; ++j) {
                        const int sl = (s + 1 + j) % 11;   // static
                        mS  = fmaf(g[j], rS[sl],  mS);
                        mD  = fmaf(g[j], rD[sl],  mD);
                        mS2 = fmaf(g[j], rS2[sl], mS2);
                        mD2 = fmaf(g[j], rD2[sl], mD2);
                    }
                    const float t1   = mS * mS, t2 = mD * mD;
                    const float a    = 0.5f  * (t1 + t2);   // mx^2 + my^2
                    const float muxy = 0.25f * (t1 - t2);   // mx * my
                    const float ep   = 0.5f  * (mS2 + mD2); // Ex2 + Ey2
                    const float eq   = 0.25f * (mS2 - mD2); // Exy
                    const float sxy  = eq - muxy;
                    const float ssum = ep - a;
                    const float num  = fmaf(2.f, muxy, C1F) * fmaf(2.f, sxy, C2F);
                    const float den  = (a + C1F) * (ssum + C2F);
                    float v = num * __builtin_amdgcn_rcpf(den + EPSF);
                    acc += fminf(fmaxf(v, 0.f), 1.f);
                }
            }
        }
    }

    // per-wave shuffle reduction + one atomic per wave (no cross-wave LDS)
    #pragma unroll
    for (int off = 32; off > 0; off >>= 1)
        acc += __shfl_down(acc, off, 64);
    if (lane == 0)
        atomicAdd(out, acc * (1.0f / (float)((size_t)NIMG * IMG_H * IMG_W)));
}

extern "C" void kernel_launch(void* const* d_in, const int* in_sizes, int n_in,
                              void* d_out, int out_size, void* d_ws, size_t ws_size,
                              hipStream_t stream) {
    const float* x = (const float*)d_in[0];
    const float* y = (const float*)d_in[1];
    const float* w = (const float*)d_in[2];
    float* out = (float*)d_out;

    // d_out is re-poisoned to 0xAA before every timed launch; zero it first.
    hipMemsetAsync(out, 0, sizeof(float), stream);

    dim3 grid(IMG_W / (4 * WC), IMG_H / RROWS, NIMG);   // (2, 16, 32)
    ssim_kernel<<<grid, dim3(256), 0, stream>>>(x, y, w, out);
}

// Round 7
// 156.572 us; speedup vs baseline: 1.0281x; 1.0281x over previous
//
#include <hip/hip_runtime.h>

// SSIM, N=32 images 512x512 fp32, 11x11 Gaussian (separable via rank-1
// window), zero pad, scalar mean output.
//
// R7: R5 skeleton (proven best: 61us) + two latency fixes. Evidence chain:
// R4->R5 halved LDS traffic (neutral), R6 removed barriers (worse 86us),
// VALUBusy stuck <=55% vs ~20us VALU floor => global-load-latency-bound
// (prefetch distance ~300cyc vs ~900cyc HBM latency; only 4 waves/SIMD).
//  - depth-2 prefetch: rows i+1, i+2 in registers; load->use ~600cyc.
//  - RROWS 16: grid (4,32,32) = 8192 waves = 32/CU = 8 waves/SIMD (max).
//    Costs +24% halo-row redundancy (ITERS/RROWS 26/16) — acceptable if
//    stalls dominate.
// Staging: (s,d)=(x+y,x-y) float2, double-buffered, 1 barrier/row; per-tap
// s^2,d^2 recover all 4 moments (verified absmax 0 since R5). 44-reg
// vertical ring, mod-11 static via 11x unroll. No min-waves launch_bounds
// (R3: 64-VGPR cap => 244MB scratch spill disaster).

#define IMG_H 512
#define IMG_W 512
#define NIMG  32
#define TW    128              // threads = own columns per block
#define RROWS 16               // output rows per block
#define ITERS (RROWS + 10)     // 26 input rows streamed
#define LDSW  (TW + 10)        // 138 staged cols (5-col halo each side)

#define C1F  1.0e-4f
#define C2F  9.0e-4f
#define EPSF 1.0e-8f

__global__ __launch_bounds__(TW) void ssim_kernel(
    const float* __restrict__ xg, const float* __restrict__ yg,
    const float* __restrict__ wg, float* __restrict__ out)
{
    const int t    = threadIdx.x;       // 0..127
    const int band = blockIdx.x;        // 0..3
    const int chnk = blockIdx.y;        // 0..31
    const int img  = blockIdx.z;        // 0..31
    const int c0   = band * TW;
    const int r0   = chnk * RROWS;

    const float* xb = xg + (size_t)img * (IMG_H * IMG_W);
    const float* yb = yg + (size_t)img * (IMG_H * IMG_W);

    __shared__ float2 ssd[2][LDSW];     // (s, d) per column, double-buffered
    __shared__ float wredS[2];

    // 1D taps = row sums of normalized 2D window -> SGPRs via readfirstlane.
    float rs = 0.f;
    {
        const int lane = t & 63;
        if (lane < 11) {
            #pragma unroll
            for (int j = 0; j < 11; ++j) rs += wg[lane * 11 + j];
        }
    }
    float g[11];
    #pragma unroll
    for (int k = 0; k < 11; ++k) {
        int gi = __shfl(__float_as_int(rs), k, 64);
        g[k] = __int_as_float(__builtin_amdgcn_readfirstlane(gi));
    }

    const int colA = c0 + t;                    // always in [0, IMG_W)
    const int  b2     = (t < 5) ? t : (TW + t); // halo buffer slot (t<10)
    const int  colB   = c0 - 5 + b2;
    const bool hasB   = (t < 10);
    const bool colBok = hasB && ((unsigned)colB < IMG_W);

    // vertical register rings: 4 planes x 11 rows = 44 VGPRs
    float rS[11], rD[11], rS2[11], rD2[11];

    // depth-2 prefetch pipeline: p0 = row about to be staged, p1 = next
    float p0xA, p0yA, p0xB, p0yB;
    float p1xA, p1yA, p1xB, p1yB;
    {
        const int r = r0 - 5;
        const bool rv = ((unsigned)r < IMG_H);
        const float* xr = xb + (size_t)r * IMG_W;
        const float* yr = yb + (size_t)r * IMG_W;
        p0xA = rv ? xr[colA] : 0.f;
        p0yA = rv ? yr[colA] : 0.f;
        p0xB = (rv && colBok) ? xr[colB] : 0.f;
        p0yB = (rv && colBok) ? yr[colB] : 0.f;
    }
    {
        const int r = r0 - 4;
        const bool rv = ((unsigned)r < IMG_H);
        const float* xr = xb + (size_t)r * IMG_W;
        const float* yr = yb + (size_t)r * IMG_W;
        p1xA = rv ? xr[colA] : 0.f;
        p1yA = rv ? yr[colA] : 0.f;
        p1xB = (rv && colBok) ? xr[colB] : 0.f;
        p1yB = (rv && colBok) ? yr[colB] : 0.f;
    }

    float acc = 0.f;

    for (int ii = 0; ii < 33; ii += 11) {
        #pragma unroll
        for (int s = 0; s < 11; ++s) {
            const int i = ii + s;
            if (i < ITERS) {
                const int pb = i & 1;
                // stage row i (from p0) in (s,d) basis
                ssd[pb][5 + t] = make_float2(p0xA + p0yA, p0xA - p0yA);
                if (hasB)
                    ssd[pb][b2] = make_float2(p0xB + p0yB, p0xB - p0yB);
                __syncthreads();

                // shift pipeline and issue load for row i+2
                p0xA = p1xA; p0yA = p1yA; p0xB = p1xB; p0yB = p1yB;
                {
                    const int r = r0 - 3 + i;
                    const bool rv = ((unsigned)r < IMG_H);
                    const float* xr = xb + (size_t)r * IMG_W;
                    const float* yr = yb + (size_t)r * IMG_W;
                    p1xA = rv ? xr[colA] : 0.f;
                    p1yA = rv ? yr[colA] : 0.f;
                    p1xB = (rv && colBok) ? xr[colB] : 0.f;
                    p1yB = (rv && colBok) ? yr[colB] : 0.f;
                }

                // horizontal 11-tap conv: per tap load (s,d), square, 4 FMA
                float hS = 0.f, hD = 0.f, hS2 = 0.f, hD2 = 0.f;
                #pragma unroll
                for (int k = 0; k < 11; ++k) {
                    const float2 v = ssd[pb][t + k];
                    hS  = fmaf(g[k], v.x, hS);
                    hD  = fmaf(g[k], v.y, hD);
                    hS2 = fmaf(g[k], v.x * v.x, hS2);
                    hD2 = fmaf(g[k], v.y * v.y, hD2);
                }
                rS[s] = hS; rD[s] = hD; rS2[s] = hS2; rD2[s] = hD2;

                if (i >= 10) {                  // output row r0 + i - 10
                    float mS = 0.f, mD = 0.f, mS2 = 0.f, mD2 = 0.f;
                    #pragma unroll
                    for (int j = 0; j < 11; ++j) {
                        const int sl = (s + 1 + j) % 11;   // static
                        mS  = fmaf(g[j], rS[sl],  mS);
                        mD  = fmaf(g[j], rD[sl],  mD);
                        mS2 = fmaf(g[j], rS2[sl], mS2);
                        mD2 = fmaf(g[j], rD2[sl], mD2);
                    }
                    const float t1   = mS * mS, t2 = mD * mD;
                    const float a    = 0.5f  * (t1 + t2);   // mx^2 + my^2
                    const float muxy = 0.25f * (t1 - t2);   // mx * my
                    const float ep   = 0.5f  * (mS2 + mD2); // Ex2 + Ey2
                    const float eq   = 0.25f * (mS2 - mD2); // Exy
                    const float sxy  = eq - muxy;
                    const float ssum = ep - a;
                    const float num  = fmaf(2.f, muxy, C1F) * fmaf(2.f, sxy, C2F);
                    const float den  = (a + C1F) * (ssum + C2F);
                    float v = num * __builtin_amdgcn_rcpf(den + EPSF);
                    acc += fminf(fmaxf(v, 0.f), 1.f);
                }
            }
        }
    }

    // block reduction: wave shuffle, then 2 slots in LDS, one atomic
    #pragma unroll
    for (int off = 32; off > 0; off >>= 1)
        acc += __shfl_down(acc, off, 64);
    __syncthreads();
    if ((t & 63) == 0) wredS[t >> 6] = acc;
    __syncthreads();
    if (t == 0) {
        const float tot = wredS[0] + wredS[1];
        atomicAdd(out, tot * (1.0f / (float)((size_t)NIMG * IMG_H * IMG_W)));
    }
}

extern "C" void kernel_launch(void* const* d_in, const int* in_sizes, int n_in,
                              void* d_out, int out_size, void* d_ws, size_t ws_size,
                              hipStream_t stream) {
    const float* x = (const float*)d_in[0];
    const float* y = (const float*)d_in[1];
    const float* w = (const float*)d_in[2];
    float* out = (float*)d_out;

    // d_out is re-poisoned to 0xAA before every timed launch; zero it first.
    hipMemsetAsync(out, 0, sizeof(float), stream);

    dim3 grid(IMG_W / TW, IMG_H / RROWS, NIMG);   // (4, 32, 32)
    ssim_kernel<<<grid, dim3(TW), 0, stream>>>(x, y, w, out);
}

// Round 8
// 118.906 us; speedup vs baseline: 1.3538x; 1.3168x over previous
//
#include <hip/hip_runtime.h>

// SSIM, N=32 images 512x512 fp32, 11x11 Gaussian (separable via rank-1
// window), zero pad, scalar mean output.
//
// R8: instruction-count attack. R5/R7 evidence: dur == VALU-busy / ~0.53
// regardless of occupancy supply or prefetch depth => issue-bound. Changes:
//  - packed fp32: all conv math on (s,d)=(x+y,x-y) pairs as ext_vector(2)
//    + __builtin_elementwise_fma -> v_pk_fma_f32 / v_pk_mul_f32
//    (gfx950 full-rate packed fp32). Horizontal 66->~34, vertical 44->22.
//  - M=2 cols/thread, TW=256 spans the whole 512-col row: 7 ds_read_b128
//    per 2 px (42 LDS-cyc/px vs 66), zero column halo (static LDS zeros at
//    row edges, no halo loads/selects/redundant fetch).
// Kept from R5 (proven): double-buffered LDS row staging, 1 barrier/row,
// depth-1 prefetch, 11x-unrolled static mod-11 register ring, per-tap
// squares recovering all 4 moments (absmax 0 since R5), no min-waves
// launch_bounds (R3 spill lesson). Grid (16,32)=512 blocks x 4 waves.

typedef float v2f __attribute__((ext_vector_type(2)));
typedef float v4f __attribute__((ext_vector_type(4)));

#define IMG_H 512
#define IMG_W 512
#define NIMG  32
#define NT    256
#define RROWS 32
#define ITERS (RROWS + 10)   // 42 input rows streamed
// LDS row: idx 0 pad | 1..5 zeroL | 6..517 data (col c -> idx 6+c) |
//          518..522 zeroR | 523 pad   (pads only ever read, never used)
#define LDSW  524

#define C1F  1.0e-4f
#define C2F  9.0e-4f
#define EPSF 1.0e-8f

static __device__ __forceinline__ v2f pkfma(float s, v2f a, v2f b) {
    v2f sv = {s, s};
    return __builtin_elementwise_fma(sv, a, b);   // -> v_pk_fma_f32
}

__global__ __launch_bounds__(NT) void ssim_kernel(
    const float* __restrict__ xg, const float* __restrict__ yg,
    const float* __restrict__ wg, float* __restrict__ out)
{
    const int t    = threadIdx.x;       // 0..255
    const int lane = t & 63;
    const int chnk = blockIdx.x;        // 0..15
    const int img  = blockIdx.y;        // 0..31
    const int r0   = chnk * RROWS;
    const int c0   = 2 * t;             // own columns c0, c0+1

    const float* xb = xg + (size_t)img * (IMG_H * IMG_W);
    const float* yb = yg + (size_t)img * (IMG_H * IMG_W);

    __shared__ alignas(16) v2f ssd[2][LDSW];   // (s,d) per column, dbuf
    __shared__ float wredS[4];

    // 1D taps = row sums of normalized 2D window -> SGPRs via readfirstlane.
    float rs = 0.f;
    if (lane < 11) {
        #pragma unroll
        for (int j = 0; j < 11; ++j) rs += wg[lane * 11 + j];
    }
    float g[11];
    #pragma unroll
    for (int k = 0; k < 11; ++k) {
        int gi = __shfl(__float_as_int(rs), k, 64);
        g[k] = __int_as_float(__builtin_amdgcn_readfirstlane(gi));
    }

    const v2f z2 = {0.f, 0.f};

    // static edge zeros (image boundary), both buffers, once; made visible
    // by the first staging __syncthreads.
    if (t < 5)        { ssd[0][1 + t]   = z2; ssd[1][1 + t]   = z2; }
    else if (t < 10)  { ssd[0][513 + t] = z2; ssd[1][513 + t] = z2; } // 518..522

    // vertical register rings: (s,d) and (s2,d2) x 2 cols x 11 rows = 88 f
    v2f rSD[11][2], rQ[11][2];

    // depth-1 prefetch (R5-proven): row r0-5
    v2f pfx, pfy;
    {
        const int r = r0 - 5;
        if ((unsigned)r < IMG_H) {
            pfx = *(const v2f*)(xb + (size_t)r * IMG_W + c0);
            pfy = *(const v2f*)(yb + (size_t)r * IMG_W + c0);
        } else { pfx = z2; pfy = z2; }
    }

    float acc = 0.f;

    for (int ii = 0; ii < 44; ii += 11) {
        #pragma unroll
        for (int s = 0; s < 11; ++s) {
            const int i = ii + s;
            if (i < ITERS) {
                const int pb = i & 1;
                // stage (sA,dA,sB,dB) as one b128 at idx 6+c0 (16B aligned)
                {
                    const v2f sv = pfx + pfy;     // v_pk_add_f32
                    const v2f dv = pfx - pfy;
                    v4f st = {sv.x, dv.x, sv.y, dv.y};
                    *(v4f*)&ssd[pb][6 + c0] = st;
                }
                __syncthreads();

                // prefetch next row (consumed next iteration)
                {
                    const int r = r0 - 4 + i;
                    if ((unsigned)r < IMG_H) {
                        pfx = *(const v2f*)(xb + (size_t)r * IMG_W + c0);
                        pfy = *(const v2f*)(yb + (size_t)r * IMG_W + c0);
                    } else { pfx = z2; pfy = z2; }
                }

                // horizontal conv, both cols. Window element j (0..13) is
                // LDS idx c0+j (col c0-6+j). Col A taps use e[1+k], col B
                // e[2+k]. 7 b128 reads; scatter-FMA, squares once per elem.
                v2f hA = z2, hB = z2, qA = z2, qB = z2;
                #pragma unroll
                for (int m = 0; m < 7; ++m) {
                    const v4f w4 = *(const v4f*)&ssd[pb][c0 + 2 * m];
                    const v2f e0 = {w4.x, w4.y};   // j = 2m
                    const v2f e1 = {w4.z, w4.w};   // j = 2m+1
                    {
                        const int j = 2 * m;
                        if (j >= 1) {
                            const v2f f0 = e0 * e0;          // v_pk_mul
                            if (j <= 11) {
                                hA = pkfma(g[j - 1], e0, hA);
                                qA = pkfma(g[j - 1], f0, qA);
                            }
                            if (j >= 2) {
                                hB = pkfma(g[j - 2], e0, hB);
                                qB = pkfma(g[j - 2], f0, qB);
                            }
                        }
                    }
                    {
                        const int j = 2 * m + 1;
                        if (j <= 12) {
                            const v2f f1 = e1 * e1;
                            if (j <= 11) {
                                hA = pkfma(g[j - 1], e1, hA);
                                qA = pkfma(g[j - 1], f1, qA);
                            }
                            if (j >= 2) {
                                hB = pkfma(g[j - 2], e1, hB);
                                qB = pkfma(g[j - 2], f1, qB);
                            }
                        }
                    }
                }
                rSD[s][0] = hA; rSD[s][1] = hB;
                rQ[s][0]  = qA; rQ[s][1]  = qB;

                if (i >= 10) {                  // output row r0 + i - 10
                    #pragma unroll
                    for (int c = 0; c < 2; ++c) {
                        v2f mSD = z2, mQ = z2;
                        #pragma unroll
                        for (int j = 0; j < 11; ++j) {
                            const int sl = (s + 1 + j) % 11;   // static
                            mSD = pkfma(g[j], rSD[sl][c], mSD);
                            mQ  = pkfma(g[j], rQ[sl][c],  mQ);
                        }
                        const v2f t2 = mSD * mSD;      // (mS^2, mD^2)
                        const float a    = 0.5f  * (t2.x + t2.y); // mx2+my2
                        const float muxy = 0.25f * (t2.x - t2.y); // mx*my
                        const float ep   = 0.5f  * (mQ.x + mQ.y); // Ex2+Ey2
                        const float eq   = 0.25f * (mQ.x - mQ.y); // Exy
                        const float sxy  = eq - muxy;
                        const float ssum = ep - a;
                        const float num  = fmaf(2.f, muxy, C1F) * fmaf(2.f, sxy, C2F);
                        const float den  = (a + C1F) * (ssum + C2F);
                        float v = num * __builtin_amdgcn_rcpf(den + EPSF);
                        acc += fminf(fmaxf(v, 0.f), 1.f);
                    }
                }
            }
        }
    }

    // block reduction: wave shuffle, 4 slots in LDS, one atomic per block
    #pragma unroll
    for (int off = 32; off > 0; off >>= 1)
        acc += __shfl_down(acc, off, 64);
    __syncthreads();
    if (lane == 0) wredS[t >> 6] = acc;
    __syncthreads();
    if (t == 0) {
        const float tot = (wredS[0] + wredS[1]) + (wredS[2] + wredS[3]);
        atomicAdd(out, tot * (1.0f / (float)((size_t)NIMG * IMG_H * IMG_W)));
    }
}

extern "C" void kernel_launch(void* const* d_in, const int* in_sizes, int n_in,
                              void* d_out, int out_size, void* d_ws, size_t ws_size,
                              hipStream_t stream) {
    const float* x = (const float*)d_in[0];
    const float* y = (const float*)d_in[1];
    const float* w = (const float*)d_in[2];
    float* out = (float*)d_out;

    // d_out is re-poisoned to 0xAA before every timed launch; zero it first.
    hipMemsetAsync(out, 0, sizeof(float), stream);

    dim3 grid(IMG_H / RROWS, NIMG);    // (16, 32) = 512 blocks x 4 waves
    ssim_kernel<<<grid, dim3(NT), 0, stream>>>(x, y, w, out);
}

// Round 9
// 116.556 us; speedup vs baseline: 1.3811x; 1.0202x over previous
//
#include <hip/hip_runtime.h>

// SSIM, N=32 images 512x512 fp32, 11x11 Gaussian (separable via rank-1
// window), zero pad, scalar mean output.
//
// R9: barrier amortization on the R8 body (R8 = 42us kernel, the proven
// best). R8 evidence: VALU busy ~16us, LDS ~13us, HBM ~7us, yet dur 42us
// with a __syncthreads + waitcnt drain EVERY row (42/wave) at only 2
// waves/SIMD -> ~26us barrier/drain dead time. Fix: stage 11-row chunks.
//  - LDS = 11 rows x 524 (s,d) v2f (46KB). Per chunk: 11 ds_write_b128,
//    barrier, issue ALL 22 next-chunk global loads (22 outstanding,
//    load->use ~= whole 3000cyc compute phase), 11 compute iterations,
//    barrier. 8 barriers total vs 42.
//  - chunk length 11 == ring modulus: ring slot = row-in-chunk, all
//    vertical indices static. 42 iters = 4 chunks, tail guarded (i<42).
//  - R8 kept: packed fp32 (v_pk_*) on (s,d)=(x+y,x-y), M=2 cols/thread,
//    TW=256 spans the row, zero column halo via per-row edge zeros
//    (written once), scatter horizontal, same epilogue + reduction.
// No min-waves launch_bounds (R3: VGPR cap => 244MB scratch spill).

typedef float v2f __attribute__((ext_vector_type(2)));
typedef float v4f __attribute__((ext_vector_type(4)));

#define IMG_H 512
#define IMG_W 512
#define NIMG  32
#define NT    256
#define RROWS 32
#define ITERS (RROWS + 10)   // 42 input rows streamed
#define CH    11             // chunk rows == ring modulus
#define NCHNK 4              // ceil(42/11)
// LDS row: idx 0 pad | 1..5 zeroL | 6..517 data (col c -> idx 6+c) |
//          518..522 zeroR | 523 pad
#define LDSW  524

#define C1F  1.0e-4f
#define C2F  9.0e-4f
#define EPSF 1.0e-8f

static __device__ __forceinline__ v2f pkfma(float s, v2f a, v2f b) {
    v2f sv = {s, s};
    return __builtin_elementwise_fma(sv, a, b);   // -> v_pk_fma_f32
}

__global__ __launch_bounds__(NT) void ssim_kernel(
    const float* __restrict__ xg, const float* __restrict__ yg,
    const float* __restrict__ wg, float* __restrict__ out)
{
    const int t    = threadIdx.x;       // 0..255
    const int lane = t & 63;
    const int chnk = blockIdx.x;        // 0..15
    const int img  = blockIdx.y;        // 0..31
    const int r0   = chnk * RROWS;
    const int c0   = 2 * t;             // own columns c0, c0+1

    const float* xb = xg + (size_t)img * (IMG_H * IMG_W);
    const float* yb = yg + (size_t)img * (IMG_H * IMG_W);

    __shared__ alignas(16) v2f ssd[CH][LDSW];   // 11-row (s,d) buffer, 46KB
    __shared__ float wredS[4];

    // 1D taps = row sums of normalized 2D window -> SGPRs via readfirstlane.
    float rs = 0.f;
    if (lane < 11) {
        #pragma unroll
        for (int j = 0; j < 11; ++j) rs += wg[lane * 11 + j];
    }
    float g[11];
    #pragma unroll
    for (int k = 0; k < 11; ++k) {
        int gi = __shfl(__float_as_int(rs), k, 64);
        g[k] = __int_as_float(__builtin_amdgcn_readfirstlane(gi));
    }

    const v2f z2 = {0.f, 0.f};

    // per-row static edge zeros (image boundary), written once; data writes
    // never touch idx 1..5 / 518..522. Visible after first barrier.
    if (t < 55)               { ssd[t / 5][1 + t % 5] = z2; }
    if (t >= 128 && t < 183)  { const int u = t - 128; ssd[u / 5][518 + u % 5] = z2; }

    // pending next-chunk loads (registers): 11 rows x (x,y) float2 = 44 VGPR
    v2f px[CH], py[CH];
    #pragma unroll
    for (int m = 0; m < CH; ++m) {
        const int r = r0 - 5 + m;
        if ((unsigned)r < IMG_H) {
            px[m] = *(const v2f*)(xb + (size_t)r * IMG_W + c0);
            py[m] = *(const v2f*)(yb + (size_t)r * IMG_W + c0);
        } else { px[m] = z2; py[m] = z2; }
    }

    // vertical register rings: (s,d),(s2,d2) x 2 cols x 11 rows = 88 floats
    v2f rSD[CH][2], rQ[CH][2];

    float acc = 0.f;

    #pragma unroll 1
    for (int c = 0; c < NCHNK; ++c) {
        // ---- write phase: convert pending rows to (s,d), stage to LDS ----
        #pragma unroll
        for (int m = 0; m < CH; ++m) {
            const v2f sv = px[m] + py[m];       // v_pk_add_f32
            const v2f dv = px[m] - py[m];
            v4f st = {sv.x, dv.x, sv.y, dv.y};
            *(v4f*)&ssd[m][6 + c0] = st;
        }
        __syncthreads();

        // ---- issue ALL next-chunk loads (consumed after next barrier) ----
        if (c < NCHNK - 1) {
            #pragma unroll
            for (int m = 0; m < CH; ++m) {
                const int r = r0 + 6 + CH * c + m;
                if ((unsigned)r < IMG_H) {
                    px[m] = *(const v2f*)(xb + (size_t)r * IMG_W + c0);
                    py[m] = *(const v2f*)(yb + (size_t)r * IMG_W + c0);
                } else { px[m] = z2; py[m] = z2; }
            }
        }

        // ---- compute phase: 11 row-iterations from LDS ----
        #pragma unroll
        for (int s = 0; s < CH; ++s) {
            const int i = CH * c + s;
            // horizontal conv, both cols; window element j (0..13) at LDS
            // idx c0+j (col c0-6+j); 7 b128 reads, squares once per elem.
            v2f hA = z2, hB = z2, qA = z2, qB = z2;
            #pragma unroll
            for (int m = 0; m < 7; ++m) {
                const v4f w4 = *(const v4f*)&ssd[s][c0 + 2 * m];
                const v2f e0 = {w4.x, w4.y};   // j = 2m
                const v2f e1 = {w4.z, w4.w};   // j = 2m+1
                {
                    const int j = 2 * m;
                    if (j >= 1) {
                        const v2f f0 = e0 * e0;          // v_pk_mul_f32
                        if (j <= 11) {
                            hA = pkfma(g[j - 1], e0, hA);
                            qA = pkfma(g[j - 1], f0, qA);
                        }
                        if (j >= 2) {
                            hB = pkfma(g[j - 2], e0, hB);
                            qB = pkfma(g[j - 2], f0, qB);
                        }
                    }
                }
                {
                    const int j = 2 * m + 1;
                    if (j <= 12) {
                        const v2f f1 = e1 * e1;
                        if (j <= 11) {
                            hA = pkfma(g[j - 1], e1, hA);
                            qA = pkfma(g[j - 1], f1, qA);
                        }
                        if (j >= 2) {
                            hB = pkfma(g[j - 2], e1, hB);
                            qB = pkfma(g[j - 2], f1, qB);
                        }
                    }
                }
            }
            rSD[s][0] = hA; rSD[s][1] = hB;
            rQ[s][0]  = qA; rQ[s][1]  = qB;

            if (i >= 10 && i < RROWS + 10) {    // output row r0 + i - 10
                #pragma unroll
                for (int cc = 0; cc < 2; ++cc) {
                    v2f mSD = z2, mQ = z2;
                    #pragma unroll
                    for (int j = 0; j < 11; ++j) {
                        const int sl = (s + 1 + j) % 11;   // static
                        mSD = pkfma(g[j], rSD[sl][cc], mSD);
                        mQ  = pkfma(g[j], rQ[sl][cc],  mQ);
                    }
                    const v2f t2 = mSD * mSD;      // (mS^2, mD^2)
                    const float a    = 0.5f  * (t2.x + t2.y); // mx2+my2
                    const float muxy = 0.25f * (t2.x - t2.y); // mx*my
                    const float ep   = 0.5f  * (mQ.x + mQ.y); // Ex2+Ey2
                    const float eq   = 0.25f * (mQ.x - mQ.y); // Exy
                    const float sxy  = eq - muxy;
                    const float ssum = ep - a;
                    const float num  = fmaf(2.f, muxy, C1F) * fmaf(2.f, sxy, C2F);
                    const float den  = (a + C1F) * (ssum + C2F);
                    float v = num * __builtin_amdgcn_rcpf(den + EPSF);
                    acc += fminf(fmaxf(v, 0.f), 1.f);
                }
            }
        }
        __syncthreads();   // protect buffer from next chunk's writes
    }

    // block reduction: wave shuffle, 4 slots in LDS, one atomic per block
    #pragma unroll
    for (int off = 32; off > 0; off >>= 1)
        acc += __shfl_down(acc, off, 64);
    if (lane == 0) wredS[t >> 6] = acc;
    __syncthreads();
    if (t == 0) {
        const float tot = (wredS[0] + wredS[1]) + (wredS[2] + wredS[3]);
        atomicAdd(out, tot * (1.0f / (float)((size_t)NIMG * IMG_H * IMG_W)));
    }
}

extern "C" void kernel_launch(void* const* d_in, const int* in_sizes, int n_in,
                              void* d_out, int out_size, void* d_ws, size_t ws_size,
                              hipStream_t stream) {
    const float* x = (const float*)d_in[0];
    const float* y = (const float*)d_in[1];
    const float* w = (const float*)d_in[2];
    float* out = (float*)d_out;

    // d_out is re-poisoned to 0xAA before every timed launch; zero it first.
    hipMemsetAsync(out, 0, sizeof(float), stream);

    dim3 grid(IMG_H / RROWS, NIMG);    // (16, 32) = 512 blocks x 4 waves
    ssim_kernel<<<grid, dim3(NT), 0, stream>>>(x, y, w, out);
}